// Round 12
// baseline (167.446 us; speedup 1.0000x reference)
//
#include <hip/hip_runtime.h>
#include <math.h>

#define NROWS 8192
#define DDIM  128
#define K20   28.853900817779268f        // 20 * log2(e)
#define K2    (K20 * K20)                // 832.5476
#define DTHR  8.3255f                    // 0.01 * K2 : diagonal mask (real pairs >= ~750)
#define JSPLIT 16                        // j-segments of 512 cols (16 tile-groups/wave)

typedef _Float16 f16x8 __attribute__((ext_vector_type(8)));
typedef _Float16 f16x4 __attribute__((ext_vector_type(4)));
typedef float    f32x16 __attribute__((ext_vector_type(16)));

// Fragment-major layout (verified R8): for 32-row group g, k-chunk kk, lane l:
//   xf[g*4096 + kk*512 + l*8 + j] = x[i = g*32 + (l&31)][k = kk*16 + (l>>5)*8 + j]
// -> a wave's 32x32x16-MFMA A/B fragment load is one contiguous 1 KB dwordx4.
// ws layout (floats after xf): sums[0..N) = nL (sum exp(-40d)), [N..2N) = nS (sum exp(-20d))

__global__ void convert_kernel(const float* __restrict__ x,
                               _Float16* __restrict__ xf,
                               float* __restrict__ sums,
                               float* __restrict__ out) {
    int idx = (blockIdx.x * 256 + threadIdx.x) * 4;    // flat (i,k) element index
    float4 v = *(const float4*)(x + idx);
    f16x4 h = { (_Float16)v.x, (_Float16)v.y, (_Float16)v.z, (_Float16)v.w };
    const int i = idx >> 7, k = idx & 127;             // k multiple of 4
    const int lane = (((k >> 3) & 1) << 5) | (i & 31);
    const int dst = (i >> 5) * 4096 + (k >> 4) * 512 + lane * 8 + (k & 7);
    *(f16x4*)(xf + dst) = h;
    if (threadIdx.x < 16) sums[blockIdx.x * 16 + threadIdx.x] = 0.0f;  // 1024*16 = 2*NROWS
    if (blockIdx.x == 0 && threadIdx.x == 0) out[0] = 0.0f;
}

// ---- main pair kernel: R8 frame + intra-wave software pipeline.
//      Barrier-free, no LDS, coalesced fragment loads. Wave owns a 32-row
//      group x 512-col segment (16 tile-groups); block's 4 waves share the
//      segment (L1 broadcast of the B stream). Per tile: two independent
//      4-MFMA chains; next tile's 8 B-loads issue between the chains and the
//      epilogue, pinned by sched_barrier so they overlap the ~300cy epilogue.
//      All pairs treated as negatives; diagonal excluded by value
//      (d2s < DTHR iff j==i). Positives fixed up in finalize_kernel. ----
__global__ __launch_bounds__(256, 4) void pair_kernel(
        const _Float16* __restrict__ xf,
        float* __restrict__ sums) {
    const int w = threadIdx.x >> 6;
    const int lane = threadIdx.x & 63;
    const int ig = blockIdx.x * 4 + w;                  // this wave's 32-row group
    const int jg0 = blockIdx.y * (256 / JSPLIT);        // first of 16 j tile-groups
    const int i0 = ig * 32;

    // A fragments: coalesced 1 KB loads (compiler may reload per tile; L1-hit)
    const _Float16* abase = xf + (size_t)ig * 4096 + lane * 8;
    f16x8 afrag[8];
    #pragma unroll
    for (int kk = 0; kk < 8; ++kk)
        afrag[kk] = *(const f16x8*)(abase + kk * 512);

    float nL[16], nS[16];
    #pragma unroll
    for (int r = 0; r < 16; ++r) { nL[r] = 0.f; nS[r] = 0.f; }

    const _Float16* bbase = xf + (size_t)jg0 * 4096 + lane * 8;

    // one tile: MFMA on bc, prefetch tile gn into bn, then epilogue
    auto tilestep = [&](const f16x8* bc, f16x8* bn, int gn) {
        f32x16 acc0 = {0.f,0.f,0.f,0.f,0.f,0.f,0.f,0.f,0.f,0.f,0.f,0.f,0.f,0.f,0.f,0.f};
        f32x16 acc1 = {0.f,0.f,0.f,0.f,0.f,0.f,0.f,0.f,0.f,0.f,0.f,0.f,0.f,0.f,0.f,0.f};
        #pragma unroll
        for (int kk = 0; kk < 4; ++kk) {
            acc0 = __builtin_amdgcn_mfma_f32_32x32x16_f16(afrag[kk],     bc[kk],     acc0, 0, 0, 0);
            acc1 = __builtin_amdgcn_mfma_f32_32x32x16_f16(afrag[kk + 4], bc[kk + 4], acc1, 0, 0, 0);
        }
        // prefetch next tile's fragments (overlaps the epilogue below)
        const _Float16* np = bbase + (size_t)gn * 4096;
        #pragma unroll
        for (int kk = 0; kk < 8; ++kk)
            bn[kk] = *(const f16x8*)(np + kk * 512);
        __builtin_amdgcn_sched_barrier(0);   // pin: loads above, epilogue below
        #pragma unroll
        for (int r = 0; r < 16; ++r) {
            float d2s = fmaf(-2.0f * K2, acc0[r] + acc1[r], 2.0f * K2);  // K20^2 * d^2
            float ds  = __builtin_amdgcn_sqrtf(d2s);             // NaN on diag, masked below
            float tt  = __builtin_amdgcn_exp2f(-ds);             // exp(-20 d)
            tt = (d2s < DTHR) ? 0.0f : tt;                       // exact diagonal exclusion
            nS[r] += tt;
            nL[r] = fmaf(tt, tt, nL[r]);                         // exp(-40 d)
        }
    };

    f16x8 bA[8], bB[8];
    #pragma unroll
    for (int kk = 0; kk < 8; ++kk)
        bA[kk] = *(const f16x8*)(bbase + kk * 512);              // tile 0

    for (int g = 0; g < 256 / JSPLIT; g += 2) {
        tilestep(bA, bB, g + 1);                                 // tile g, prefetch g+1
        tilestep(bB, bA, (g + 2) & (256 / JSPLIT - 1));          // tile g+1, prefetch g+2
    }

    // reduce across the 32 column-lanes; lanes 0 / 32 hold 16 row-sums each
    #pragma unroll
    for (int r = 0; r < 16; ++r) {
        float a = nL[r], b = nS[r];
        #pragma unroll
        for (int m = 1; m < 32; m <<= 1) {
            a += __shfl_xor(a, m, 64);
            b += __shfl_xor(b, m, 64);
        }
        if ((lane & 31) == 0) {
            const int row = (r & 3) + 8 * (r >> 2) + 4 * (lane >> 5);  // C/D row map (m74/m101)
            atomicAdd(&sums[i0 + row], a);
            atomicAdd(&sums[NROWS + i0 + row], b);
        }
    }
}

// ---- finalize + positive-pair correction (frag-major reads), unchanged R8 ----
__global__ void finalize_kernel(const _Float16* __restrict__ xf,
                                const float* __restrict__ sums,
                                float* __restrict__ out) {
    const int i = blockIdx.x * 256 + threadIdx.x;
    const int g = i >> 5, ri = i & 31;
    const int ii = i & 7;

    f16x8 xi[16];
    #pragma unroll
    for (int kk = 0; kk < 8; ++kk) {
        xi[kk * 2]     = *(const f16x8*)(xf + g * 4096 + kk * 512 + ri * 8);
        xi[kk * 2 + 1] = *(const f16x8*)(xf + g * 4096 + kk * 512 + (32 + ri) * 8);
    }

    float pL = 0.f, pS = 0.f, subL = 0.f, subS = 0.f;
    #pragma unroll
    for (int jj = 0; jj < 8; ++jj) {
        if (jj == ii) continue;
        const int rj = ri - ii + jj;               // same 32-row group (classes 8-aligned)
        float dot = 0.f;
        #pragma unroll
        for (int kk = 0; kk < 8; ++kk) {
            f16x8 b0 = *(const f16x8*)(xf + g * 4096 + kk * 512 + rj * 8);
            f16x8 b1 = *(const f16x8*)(xf + g * 4096 + kk * 512 + (32 + rj) * 8);
            #pragma unroll
            for (int u = 0; u < 8; ++u) {
                dot = fmaf((float)xi[kk * 2][u],     (float)b0[u], dot);
                dot = fmaf((float)xi[kk * 2 + 1][u], (float)b1[u], dot);
            }
        }
        float d2 = fmaf(-2.f, dot, 2.f);
        float d  = sqrtf(fmaxf(d2, 1e-12f));           // reference clamp
        float tt = __builtin_amdgcn_exp2f(-d * K20);   // exp(-20 d)
        pS += __builtin_amdgcn_exp2f(d * K20);         // exp(+20 d)
        pL = fmaf(tt, tt, pL);
        float tp = (d2 * K2 < DTHR) ? 0.f : tt;        // what pair_kernel added
        subS += tp;
        subL = fmaf(tp, tp, subL);
    }

    float nL = sums[i] - subL;
    float nS = sums[NROWS + i] - subS;
    float aLr  = 1.0f - pL / (pL + nL);
    float posL = logf(pS) - 16.0f;    // log(sum exp(20(d-0.8)))
    float negL = logf(nS) + 22.0f;    // log(sum exp(20(1.1-d)))
    float v = aLr * (posL + negL);

    #pragma unroll
    for (int m = 32; m; m >>= 1) v += __shfl_xor(v, m, 64);
    __shared__ float partial[4];
    int wv = threadIdx.x >> 6, lane = threadIdx.x & 63;
    if (lane == 0) partial[wv] = v;
    __syncthreads();
    if (threadIdx.x == 0) {
        float s = partial[0] + partial[1] + partial[2] + partial[3];
        atomicAdd(out, s * (1.0f / NROWS));
    }
}

extern "C" void kernel_launch(void* const* d_in, const int* in_sizes, int n_in,
                              void* d_out, int out_size, void* d_ws, size_t ws_size,
                              hipStream_t stream) {
    const float* x = (const float*)d_in[0];
    float* out = (float*)d_out;

    _Float16* xf = (_Float16*)d_ws;              // 2 MB, fragment-major
    float* sums  = (float*)(xf + NROWS * DDIM);  // 2*NROWS floats

    convert_kernel<<<NROWS * DDIM / (256 * 4), 256, 0, stream>>>(x, xf, sums, out);
    dim3 grid(NROWS / (4 * 32), JSPLIT);         // 64 x 16 = 1024 blocks = 4096 waves (4/SIMD)
    pair_kernel<<<grid, 256, 0, stream>>>(xf, sums);
    finalize_kernel<<<NROWS / 256, 256, 0, stream>>>(xf, sums, out);
}

// Round 13
// 104.908 us; speedup vs baseline: 1.5961x; 1.5961x over previous
//
#include <hip/hip_runtime.h>
#include <math.h>

#define NROWS 8192
#define DDIM  128
#define K20   28.853900817779268f        // 20 * log2(e)
#define K2    (K20 * K20)                // 832.5476
#define DTHR  8.3255f                    // 0.01 * K2 : diagonal mask (real pairs >= ~750)
#define JSPLIT 32                        // j-segments of 256 cols (8 tiles/wave)

typedef _Float16 f16x8 __attribute__((ext_vector_type(8)));
typedef _Float16 f16x4 __attribute__((ext_vector_type(4)));
typedef float    f32x16 __attribute__((ext_vector_type(16)));

// Fragment-major layout (verified R8): for 32-row group g, k-chunk kk, lane l:
//   xf[g*4096 + kk*512 + l*8 + j] = x[i = g*32 + (l&31)][k = kk*16 + (l>>5)*8 + j]
// -> a wave's 32x32x16-MFMA A/B fragment load is one contiguous 1 KB dwordx4.
//
// part layout (floats after xf), NO zero-init needed (every slot written once):
//   part[s*NROWS + i]                  = nL partial from j-segment s
//   part[JSPLIT*NROWS + s*NROWS + i]   = nS partial from j-segment s

__global__ void convert_kernel(const float* __restrict__ x,
                               _Float16* __restrict__ xf,
                               float* __restrict__ out) {
    int idx = (blockIdx.x * 256 + threadIdx.x) * 4;    // flat (i,k) element index
    float4 v = *(const float4*)(x + idx);
    f16x4 h = { (_Float16)v.x, (_Float16)v.y, (_Float16)v.z, (_Float16)v.w };
    const int i = idx >> 7, k = idx & 127;             // k multiple of 4
    const int lane = (((k >> 3) & 1) << 5) | (i & 31);
    const int dst = (i >> 5) * 4096 + (k >> 4) * 512 + lane * 8 + (k & 7);
    *(f16x4*)(xf + dst) = h;
    if (blockIdx.x == 0 && threadIdx.x == 0) out[0] = 0.0f;
}

// ---- main pair kernel: R8 frame at 8 blocks/CU, zero atomics.
//      Barrier-free, no LDS, coalesced fragment loads. Wave (ig, s) owns a
//      32-row group x 256-col segment (8 tiles); the block's 4 waves share
//      the segment (L1 broadcast of the B stream). Two independent 4-MFMA
//      chains. All pairs treated as negatives; diagonal excluded by value
//      (d2s < DTHR iff j==i). Positives fixed up in finalize_kernel.
//      Each wave stores its 64 row-sums to a private slice: 4 full cache
//      lines, non-atomic, contention-free. ----
__global__ __launch_bounds__(256, 4) void pair_kernel(
        const _Float16* __restrict__ xf,
        float* __restrict__ part) {
    const int w = threadIdx.x >> 6;
    const int lane = threadIdx.x & 63;
    const int ig = blockIdx.x * 4 + w;                  // this wave's 32-row group
    const int s  = blockIdx.y;                          // j-segment 0..31
    const int jg0 = s * 8;
    const int i0 = ig * 32;

    // A fragments: coalesced 1 KB loads (reloads are L1-hit)
    const _Float16* abase = xf + (size_t)ig * 4096 + lane * 8;
    f16x8 afrag[8];
    #pragma unroll
    for (int kk = 0; kk < 8; ++kk)
        afrag[kk] = *(const f16x8*)(abase + kk * 512);

    float nL[16], nS[16];
    #pragma unroll
    for (int r = 0; r < 16; ++r) { nL[r] = 0.f; nS[r] = 0.f; }

    const _Float16* bbase = xf + (size_t)jg0 * 4096 + lane * 8;
    for (int g = 0; g < 8; ++g) {
        const _Float16* bp = bbase + (size_t)g * 4096;
        f16x8 b[8];
        #pragma unroll
        for (int kk = 0; kk < 8; ++kk)
            b[kk] = *(const f16x8*)(bp + kk * 512);     // contiguous 1 KB per instr

        // two independent 4-MFMA chains (half the serial chain latency)
        f32x16 acc0 = {0.f,0.f,0.f,0.f,0.f,0.f,0.f,0.f,0.f,0.f,0.f,0.f,0.f,0.f,0.f,0.f};
        f32x16 acc1 = {0.f,0.f,0.f,0.f,0.f,0.f,0.f,0.f,0.f,0.f,0.f,0.f,0.f,0.f,0.f,0.f};
        #pragma unroll
        for (int kk = 0; kk < 4; ++kk) {
            acc0 = __builtin_amdgcn_mfma_f32_32x32x16_f16(afrag[kk],     b[kk],     acc0, 0, 0, 0);
            acc1 = __builtin_amdgcn_mfma_f32_32x32x16_f16(afrag[kk + 4], b[kk + 4], acc1, 0, 0, 0);
        }

        // uniform epilogue (R8-proven codegen)
        #pragma unroll
        for (int r = 0; r < 16; ++r) {
            float d2s = fmaf(-2.0f * K2, acc0[r] + acc1[r], 2.0f * K2);  // K20^2 * d^2
            float ds  = __builtin_amdgcn_sqrtf(d2s);             // NaN on diag, masked below
            float tt  = __builtin_amdgcn_exp2f(-ds);             // exp(-20 d)
            tt = (d2s < DTHR) ? 0.0f : tt;                       // exact diagonal exclusion
            nS[r] += tt;
            nL[r] = fmaf(tt, tt, nL[r]);                         // exp(-40 d)
        }
    }

    // reduce across the 32 column-lanes; lanes 0 / 32 hold 16 row-sums each,
    // stored non-atomically to this (ig, s) wave's private slice.
    #pragma unroll
    for (int r = 0; r < 16; ++r) {
        float a = nL[r], b = nS[r];
        #pragma unroll
        for (int m = 1; m < 32; m <<= 1) {
            a += __shfl_xor(a, m, 64);
            b += __shfl_xor(b, m, 64);
        }
        if ((lane & 31) == 0) {
            const int row = i0 + (r & 3) + 8 * (r >> 2) + 4 * (lane >> 5);  // C/D row map
            part[(size_t)s * NROWS + row] = a;
            part[(size_t)JSPLIT * NROWS + (size_t)s * NROWS + row] = b;
        }
    }
}

// ---- finalize: reduce the 32 per-segment slices, positive-pair correction
//      (frag-major reads), loss, mean. Block owns 256 rows = 32 classes. ----
__global__ void finalize_kernel(const _Float16* __restrict__ xf,
                                const float* __restrict__ part,
                                float* __restrict__ out) {
    const int i = blockIdx.x * 256 + threadIdx.x;
    const int g = i >> 5, ri = i & 31;
    const int ii = i & 7;

    float nLs = 0.f, nSs = 0.f;
    #pragma unroll 8
    for (int s = 0; s < JSPLIT; ++s) {
        nLs += part[(size_t)s * NROWS + i];
        nSs += part[(size_t)JSPLIT * NROWS + (size_t)s * NROWS + i];
    }

    f16x8 xi[16];
    #pragma unroll
    for (int kk = 0; kk < 8; ++kk) {
        xi[kk * 2]     = *(const f16x8*)(xf + g * 4096 + kk * 512 + ri * 8);
        xi[kk * 2 + 1] = *(const f16x8*)(xf + g * 4096 + kk * 512 + (32 + ri) * 8);
    }

    float pL = 0.f, pS = 0.f, subL = 0.f, subS = 0.f;
    #pragma unroll
    for (int jj = 0; jj < 8; ++jj) {
        if (jj == ii) continue;
        const int rj = ri - ii + jj;               // same 32-row group (classes 8-aligned)
        float dot = 0.f;
        #pragma unroll
        for (int kk = 0; kk < 8; ++kk) {
            f16x8 b0 = *(const f16x8*)(xf + g * 4096 + kk * 512 + rj * 8);
            f16x8 b1 = *(const f16x8*)(xf + g * 4096 + kk * 512 + (32 + rj) * 8);
            #pragma unroll
            for (int u = 0; u < 8; ++u) {
                dot = fmaf((float)xi[kk * 2][u],     (float)b0[u], dot);
                dot = fmaf((float)xi[kk * 2 + 1][u], (float)b1[u], dot);
            }
        }
        float d2 = fmaf(-2.f, dot, 2.f);
        float d  = sqrtf(fmaxf(d2, 1e-12f));           // reference clamp
        float tt = __builtin_amdgcn_exp2f(-d * K20);   // exp(-20 d)
        pS += __builtin_amdgcn_exp2f(d * K20);         // exp(+20 d)
        pL = fmaf(tt, tt, pL);
        float tp = (d2 * K2 < DTHR) ? 0.f : tt;        // what pair_kernel added
        subS += tp;
        subL = fmaf(tp, tp, subL);
    }

    float nL = nLs - subL;
    float nS = nSs - subS;
    float aLr  = 1.0f - pL / (pL + nL);
    float posL = logf(pS) - 16.0f;    // log(sum exp(20(d-0.8)))
    float negL = logf(nS) + 22.0f;    // log(sum exp(20(1.1-d)))
    float v = aLr * (posL + negL);

    #pragma unroll
    for (int m = 32; m; m >>= 1) v += __shfl_xor(v, m, 64);
    __shared__ float partial[4];
    int wv = threadIdx.x >> 6, lane = threadIdx.x & 63;
    if (lane == 0) partial[wv] = v;
    __syncthreads();
    if (threadIdx.x == 0) {
        float ssum = partial[0] + partial[1] + partial[2] + partial[3];
        atomicAdd(out, ssum * (1.0f / NROWS));
    }
}

extern "C" void kernel_launch(void* const* d_in, const int* in_sizes, int n_in,
                              void* d_out, int out_size, void* d_ws, size_t ws_size,
                              hipStream_t stream) {
    const float* x = (const float*)d_in[0];
    float* out = (float*)d_out;

    _Float16* xf = (_Float16*)d_ws;              // 2 MB, fragment-major
    float* part  = (float*)(xf + NROWS * DDIM);  // 2*JSPLIT*NROWS floats = 2 MB

    convert_kernel<<<NROWS * DDIM / (256 * 4), 256, 0, stream>>>(x, xf, out);
    dim3 grid(NROWS / (4 * 32), JSPLIT);         // 64 x 32 = 2048 blocks = 8 blocks/CU
    pair_kernel<<<grid, 256, 0, stream>>>(xf, part);
    finalize_kernel<<<NROWS / 256, 256, 0, stream>>>(xf, part, out);
}